// Round 1
// baseline (371.297 us; speedup 1.0000x reference)
//
#include <hip/hip_runtime.h>
#include <hip/hip_bf16.h>
#include <math.h>

#define NUM_B 4
#define SEQ 512
#define HID 1024
#define NH 50          // 2 ent + 24 head + 24 tail
#define NCOL 6400      // NH * 128
#define M_TOK 2048     // NUM_B * SEQ

typedef short bf16x8_t __attribute__((ext_vector_type(8)));
typedef float f32x4_t __attribute__((ext_vector_type(4)));

__device__ __forceinline__ unsigned short f2bf(float f) {
    union { float f; unsigned int u; } v; v.f = f;
    unsigned int u = v.u;
    u += 0x7fffu + ((u >> 16) & 1u);
    return (unsigned short)(u >> 16);
}
__device__ __forceinline__ float bf2f(unsigned short h) {
    union { unsigned int u; float f; } v; v.u = ((unsigned int)h) << 16;
    return v.f;
}

__device__ __forceinline__ void gload_lds16(const void* g, void* l) {
    __builtin_amdgcn_global_load_lds(
        (__attribute__((address_space(1))) unsigned int*)(unsigned long long)g,
        (__attribute__((address_space(3))) unsigned int*)(unsigned long long)(uintptr_t)l,
        16, 0, 0);
}

// ---------------- RoPE tables: cosT/sinT [1024][32] ----------------
__global__ void k_tables(float* cosT, float* sinT) {
    int idx = blockIdx.x * blockDim.x + threadIdx.x;   // 32768
    int p = idx >> 5, j = idx & 31;
    float div = expf(-logf(10000.f) * (float)(2 * (j >> 1)) / 32.f);
    float ang = (float)p * div;
    cosT[idx] = cosf(ang);
    sinT[idx] = sinf(ang);
}

// ---------------- x fp32 -> bf16 ----------------
__global__ void k_cvt_x(const float* __restrict__ x, unsigned short* __restrict__ xb) {
    int i = blockIdx.x * blockDim.x + threadIdx.x;     // 524288, 4 elems each
    float4 v = ((const float4*)x)[i];
    ushort4 o;
    o.x = f2bf(v.x); o.y = f2bf(v.y); o.z = f2bf(v.z); o.w = f2bf(v.w);
    ((ushort4*)xb)[i] = o;
}

// ---------------- W (K x N) -> Wt (N x K) bf16, tiled transpose ----------------
__global__ void k_cvt_w(const float* __restrict__ W, unsigned short* __restrict__ Wt,
                        int N, int n_off) {
    __shared__ float t[32][33];
    int n = blockIdx.x * 32 + threadIdx.x;
    int k = blockIdx.y * 32 + threadIdx.y;
    t[threadIdx.y][threadIdx.x] = W[(size_t)k * N + n];
    __syncthreads();
    int on = blockIdx.x * 32 + threadIdx.y;
    int ok = blockIdx.y * 32 + threadIdx.x;
    Wt[(size_t)(n_off + on) * HID + ok] = f2bf(t[threadIdx.x][threadIdx.y]);
}

// ---------------- concat biases into ball[6400] ----------------
__global__ void k_bias(const float* __restrict__ be, const float* __restrict__ bh,
                       const float* __restrict__ bt, float* __restrict__ ball) {
    int i = blockIdx.x * blockDim.x + threadIdx.x;
    if (i < 256) ball[i] = be[i];
    else if (i < 3328) ball[i] = bh[i - 256];
    else ball[i] = bt[i - 3328];
}

// ---------------- GEMM1: seq[2048][6400] = x_bf @ Wt^T + bias ----------------
// 128x128 tile, BK=64, 4 waves each 64x64 quadrant, XOR-swizzled LDS chunks.
__global__ __launch_bounds__(256) void k_gemm1(const unsigned short* __restrict__ A,
                                               const unsigned short* __restrict__ Bt,
                                               const float* __restrict__ bias,
                                               unsigned short* __restrict__ seq) {
    __shared__ __align__(16) unsigned short As[128 * 64];
    __shared__ __align__(16) unsigned short Bs[128 * 64];
    int tid = threadIdx.x;
    int wave = tid >> 6, lane = tid & 63;
    int l15 = lane & 15, q = lane >> 4;
    int m0 = blockIdx.x * 128, n0 = blockIdx.y * 128;
    int wm = (wave >> 1) * 64, wn = (wave & 1) * 64;

    f32x4_t acc[4][4];
#pragma unroll
    for (int i = 0; i < 4; i++)
#pragma unroll
        for (int j = 0; j < 4; j++) acc[i][j] = (f32x4_t){0.f, 0.f, 0.f, 0.f};

    for (int k0 = 0; k0 < HID; k0 += 64) {
        __syncthreads();
#pragma unroll
        for (int it = 0; it < 4; ++it) {
            int c = it * 256 + tid;            // 0..1023 chunk of 16B
            int r = c >> 3, cl = c & 7;
            int cg = cl ^ (r & 7);             // swizzle: LDS(r,cl) holds global chunk cg
            gload_lds16(A + (size_t)(m0 + r) * HID + k0 + cg * 8, As + c * 8);
            gload_lds16(Bt + (size_t)(n0 + r) * HID + k0 + cg * 8, Bs + c * 8);
        }
        __syncthreads();
#pragma unroll
        for (int ks = 0; ks < 2; ++ks) {
            bf16x8_t af[4], bfr[4];
#pragma unroll
            for (int i = 0; i < 4; i++) {
                int r = wm + i * 16 + l15;
                int cl = (ks * 4 + q) ^ (r & 7);
                af[i] = *(const bf16x8_t*)&As[r * 64 + cl * 8];
            }
#pragma unroll
            for (int j = 0; j < 4; j++) {
                int r = wn + j * 16 + l15;
                int cl = (ks * 4 + q) ^ (r & 7);
                bfr[j] = *(const bf16x8_t*)&Bs[r * 64 + cl * 8];
            }
#pragma unroll
            for (int i = 0; i < 4; i++)
#pragma unroll
                for (int j = 0; j < 4; j++)
                    acc[i][j] = __builtin_amdgcn_mfma_f32_16x16x32_bf16(af[i], bfr[j], acc[i][j], 0, 0, 0);
        }
    }
    // epilogue: + bias, write bf16
#pragma unroll
    for (int j = 0; j < 4; j++) {
        int n = n0 + wn + j * 16 + l15;
        float bv = bias[n];
#pragma unroll
        for (int i = 0; i < 4; i++)
#pragma unroll
            for (int r = 0; r < 4; r++) {
                int m = m0 + wm + i * 16 + q * 4 + r;
                seq[(size_t)m * NCOL + n] = f2bf(acc[i][j][r] + bv);
            }
    }
}

// ---------------- RoPE in-place on seq (paired even/odd dims) ----------------
__global__ void k_rope(unsigned short* __restrict__ seq, const int* __restrict__ xp,
                       const int* __restrict__ yp, const float* __restrict__ cosT,
                       const float* __restrict__ sinT) {
    int t = blockIdx.x * blockDim.x + threadIdx.x;  // 2048*3200 pairs
    int m = t / 3200;
    int p = t - m * 3200;
    int n = p * 2;
    int dd = n & 63;
    int pos = (dd < 32) ? xp[m] : yp[m];
    int tj = dd & 31;
    float c = cosT[pos * 32 + tj];
    float s = sinT[pos * 32 + tj];
    unsigned int v = *(unsigned int*)&seq[(size_t)m * NCOL + n];
    float q0 = bf2f((unsigned short)(v & 0xffffu));
    float q1 = bf2f((unsigned short)(v >> 16));
    float r0 = q0 * c - q1 * s;
    float r1 = q1 * c + q0 * s;
    unsigned int o = (unsigned int)f2bf(r0) | ((unsigned int)f2bf(r1) << 16);
    *(unsigned int*)&seq[(size_t)m * NCOL + n] = o;
}

// ---------------- attention: out[b][h][m][n] = (Q.Kt - tril*1e12)/8 ----------------
__global__ __launch_bounds__(256) void k_attn(const unsigned short* __restrict__ seq,
                                              const int* __restrict__ mask,
                                              float* __restrict__ out) {
    __shared__ __align__(16) unsigned short Qs[128 * 64];
    __shared__ __align__(16) unsigned short Ks[128 * 64];
    int tid = threadIdx.x;
    int bh = blockIdx.z;
    int b = bh / NH, h = bh - b * NH;
    int m0 = blockIdx.x * 128, n0 = blockIdx.y * 128;
    const unsigned short* qbase = seq + (size_t)b * SEQ * NCOL + h * 128;

#pragma unroll
    for (int it = 0; it < 4; ++it) {
        int c = it * 256 + tid;
        int r = c >> 3, cl = c & 7;
        int cg = cl ^ (r & 7);
        gload_lds16(qbase + (size_t)(m0 + r) * NCOL + cg * 8, Qs + c * 8);
        gload_lds16(qbase + (size_t)(n0 + r) * NCOL + 64 + cg * 8, Ks + c * 8);
    }
    __syncthreads();

    int wave = tid >> 6, lane = tid & 63;
    int l15 = lane & 15, q = lane >> 4;
    int wm = (wave >> 1) * 64, wn = (wave & 1) * 64;

    f32x4_t acc[4][4];
#pragma unroll
    for (int i = 0; i < 4; i++)
#pragma unroll
        for (int j = 0; j < 4; j++) acc[i][j] = (f32x4_t){0.f, 0.f, 0.f, 0.f};

#pragma unroll
    for (int ks = 0; ks < 2; ++ks) {
        bf16x8_t af[4], bfr[4];
#pragma unroll
        for (int i = 0; i < 4; i++) {
            int r = wm + i * 16 + l15;
            int cl = (ks * 4 + q) ^ (r & 7);
            af[i] = *(const bf16x8_t*)&Qs[r * 64 + cl * 8];
        }
#pragma unroll
        for (int j = 0; j < 4; j++) {
            int r = wn + j * 16 + l15;
            int cl = (ks * 4 + q) ^ (r & 7);
            bfr[j] = *(const bf16x8_t*)&Ks[r * 64 + cl * 8];
        }
#pragma unroll
        for (int i = 0; i < 4; i++)
#pragma unroll
            for (int j = 0; j < 4; j++)
                acc[i][j] = __builtin_amdgcn_mfma_f32_16x16x32_bf16(af[i], bfr[j], acc[i][j], 0, 0, 0);
    }

    const int* mrow = mask + b * SEQ;
    bool ent = (h < 2);
    size_t obase = (size_t)bh * SEQ * SEQ;
#pragma unroll
    for (int j = 0; j < 4; j++) {
        int n = n0 + wn + j * 16 + l15;
        int maskn = mrow[n];
#pragma unroll
        for (int i = 0; i < 4; i++)
#pragma unroll
            for (int r = 0; r < 4; r++) {
                int m = m0 + wm + i * 16 + q * 4 + r;
                float v = acc[i][j][r] * 0.125f;
                if (ent && m > n) v -= 1.25e11f;
                if (mrow[m] == 0 || maskn == 0) v = -INFINITY;
                out[obase + (size_t)m * SEQ + n] = v;
            }
    }
}

extern "C" void kernel_launch(void* const* d_in, const int* in_sizes, int n_in,
                              void* d_out, int out_size, void* d_ws, size_t ws_size,
                              hipStream_t stream) {
    const float* x      = (const float*)d_in[0];
    const int*   mask   = (const int*)d_in[1];
    const int*   xp     = (const int*)d_in[2];
    const int*   yp     = (const int*)d_in[3];
    const float* W_ent  = (const float*)d_in[4];
    const float* b_ent  = (const float*)d_in[5];
    const float* W_head = (const float*)d_in[6];
    const float* b_head = (const float*)d_in[7];
    const float* W_tail = (const float*)d_in[8];
    const float* b_tail = (const float*)d_in[9];
    float* out = (float*)d_out;

    char* ws = (char*)d_ws;
    size_t off = 0;
    auto alloc = [&](size_t bytes) {
        void* p = ws + off;
        off += (bytes + 255) & ~(size_t)255;
        return p;
    };
    float* cosT = (float*)alloc(32768 * 4);
    float* sinT = (float*)alloc(32768 * 4);
    unsigned short* xb  = (unsigned short*)alloc((size_t)M_TOK * HID * 2);
    unsigned short* Wt  = (unsigned short*)alloc((size_t)NCOL * HID * 2);
    float* ball = (float*)alloc(NCOL * 4);
    unsigned short* seq = (unsigned short*)alloc((size_t)M_TOK * NCOL * 2);

    k_tables<<<128, 256, 0, stream>>>(cosT, sinT);
    k_cvt_x<<<2048, 256, 0, stream>>>(x, xb);
    dim3 tb(32, 32);
    k_cvt_w<<<dim3(8, 32), tb, 0, stream>>>(W_ent, Wt, 256, 0);
    k_cvt_w<<<dim3(96, 32), tb, 0, stream>>>(W_head, Wt, 3072, 256);
    k_cvt_w<<<dim3(96, 32), tb, 0, stream>>>(W_tail, Wt, 3072, 3328);
    k_bias<<<25, 256, 0, stream>>>(b_ent, b_head, b_tail, ball);
    k_gemm1<<<dim3(16, 50), 256, 0, stream>>>(xb, Wt, ball, seq);
    k_rope<<<25600, 256, 0, stream>>>(seq, xp, yp, cosT, sinT);
    k_attn<<<dim3(4, 4, 200), 256, 0, stream>>>(seq, mask, out);
}

// Round 2
// 326.532 us; speedup vs baseline: 1.1371x; 1.1371x over previous
//
#include <hip/hip_runtime.h>
#include <hip/hip_bf16.h>
#include <math.h>

#define NUM_B 4
#define SEQ 512
#define HID 1024
#define NH 50          // 2 ent + 24 head + 24 tail
#define NCOL 6400      // NH * 128
#define M_TOK 2048     // NUM_B * SEQ

typedef short bf16x8_t __attribute__((ext_vector_type(8)));
typedef float f32x4_t __attribute__((ext_vector_type(4)));

__device__ __forceinline__ unsigned short f2bf(float f) {
    union { float f; unsigned int u; } v; v.f = f;
    unsigned int u = v.u;
    u += 0x7fffu + ((u >> 16) & 1u);
    return (unsigned short)(u >> 16);
}

__device__ __forceinline__ void gload_lds16(const void* g, void* l) {
    __builtin_amdgcn_global_load_lds(
        (__attribute__((address_space(1))) unsigned int*)(unsigned long long)g,
        (__attribute__((address_space(3))) unsigned int*)(unsigned long long)(uintptr_t)l,
        16, 0, 0);
}

// ---------------- prep: x fp32->bf16, packed cos/sin table, bias concat -----
// csT[p*16 + t2] = (cos(p*div[t2]), sin(p*div[t2])), t2 = (dim&31)>>1
__global__ void k_prep(const float* __restrict__ x, unsigned short* __restrict__ xb,
                       float2* __restrict__ csT,
                       const float* __restrict__ be, const float* __restrict__ bh,
                       const float* __restrict__ bt, float* __restrict__ ball) {
    int bid = blockIdx.x, tid = threadIdx.x;
    if (bid < 2048) {                       // x convert: 2048*256 float4
        int i = bid * 256 + tid;
        float4 v = ((const float4*)x)[i];
        ushort4 o;
        o.x = f2bf(v.x); o.y = f2bf(v.y); o.z = f2bf(v.z); o.w = f2bf(v.w);
        ((ushort4*)xb)[i] = o;
    } else if (bid < 2112) {                // cos/sin table: 1024*16 entries
        int idx = (bid - 2048) * 256 + tid;
        int p = idx >> 4, t2 = idx & 15;
        float ang = (float)p * expf(-logf(10000.f) * (float)(2 * t2) / 32.f);
        csT[idx] = make_float2(cosf(ang), sinf(ang));
    } else {                                // bias concat: 6400
        int i = (bid - 2112) * 256 + tid;
        if (i < 6400) {
            float v;
            if (i < 256) v = be[i];
            else if (i < 3328) v = bh[i - 256];
            else v = bt[i - 3328];
            ball[i] = v;
        }
    }
}

// ---------------- all W (K x Nw) -> Wt (6400 x 1024) bf16 transpose ---------
__global__ void k_cvt_w(const float* __restrict__ We, const float* __restrict__ Wh,
                        const float* __restrict__ Wl, unsigned short* __restrict__ Wo) {
    __shared__ float t[32][33];
    int n = blockIdx.x * 32 + threadIdx.x;     // segments are 32-aligned
    const float* W; int Nw, nc;
    if (n < 256)       { W = We; Nw = 256;  nc = n; }
    else if (n < 3328) { W = Wh; Nw = 3072; nc = n - 256; }
    else               { W = Wl; Nw = 3072; nc = n - 3328; }
    int k = blockIdx.y * 32 + threadIdx.y;
    t[threadIdx.y][threadIdx.x] = W[(size_t)k * Nw + nc];
    __syncthreads();
    int on = blockIdx.x * 32 + threadIdx.y;
    int ok = blockIdx.y * 32 + threadIdx.x;
    Wo[(size_t)on * HID + ok] = f2bf(t[threadIdx.x][threadIdx.y]);
}

// ---------------- GEMM1 + bias + RoPE fused: seq[2048][6400] ----------------
// 128x128 tile, BK=64, swapped MFMA operands: acc rows = n (q*4+r), cols = m (l15)
__global__ __launch_bounds__(256) void k_gemm1(const unsigned short* __restrict__ A,
                                               const unsigned short* __restrict__ Bt,
                                               const float* __restrict__ bias,
                                               const int* __restrict__ xp,
                                               const int* __restrict__ yp,
                                               const float2* __restrict__ csT,
                                               unsigned short* __restrict__ seq) {
    __shared__ __align__(16) unsigned short As[128 * 64];
    __shared__ __align__(16) unsigned short Bs[128 * 64];
    int tid = threadIdx.x;
    int wave = tid >> 6, lane = tid & 63;
    int l15 = lane & 15, q = lane >> 4;
    int m0 = blockIdx.x * 128, n0 = blockIdx.y * 128;
    int wm = (wave >> 1) * 64, wn = (wave & 1) * 64;

    f32x4_t acc[4][4];
#pragma unroll
    for (int i = 0; i < 4; i++)
#pragma unroll
        for (int j = 0; j < 4; j++) acc[i][j] = (f32x4_t){0.f, 0.f, 0.f, 0.f};

    for (int k0 = 0; k0 < HID; k0 += 64) {
        __syncthreads();
#pragma unroll
        for (int it = 0; it < 4; ++it) {
            int c = it * 256 + tid;            // chunk of 16B
            int r = c >> 3, cl = c & 7;
            int cg = cl ^ (r & 7);             // XOR swizzle
            gload_lds16(A + (size_t)(m0 + r) * HID + k0 + cg * 8, As + c * 8);
            gload_lds16(Bt + (size_t)(n0 + r) * HID + k0 + cg * 8, Bs + c * 8);
        }
        __syncthreads();
#pragma unroll
        for (int ks = 0; ks < 2; ++ks) {
            bf16x8_t af[4], bfr[4];
#pragma unroll
            for (int i = 0; i < 4; i++) {
                int r = wm + i * 16 + l15;
                int cl = (ks * 4 + q) ^ (r & 7);
                af[i] = *(const bf16x8_t*)&As[r * 64 + cl * 8];
            }
#pragma unroll
            for (int j = 0; j < 4; j++) {
                int r = wn + j * 16 + l15;
                int cl = (ks * 4 + q) ^ (r & 7);
                bfr[j] = *(const bf16x8_t*)&Bs[r * 64 + cl * 8];
            }
#pragma unroll
            for (int i = 0; i < 4; i++)
#pragma unroll
                for (int j = 0; j < 4; j++)
                    acc[i][j] = __builtin_amdgcn_mfma_f32_16x16x32_bf16(bfr[j], af[i], acc[i][j], 0, 0, 0);
        }
    }

    // epilogue: + bias, RoPE (lane-local pairs), ushort4 store
    float4 bj[4];
#pragma unroll
    for (int j = 0; j < 4; j++)
        bj[j] = *(const float4*)&bias[n0 + wn + j * 16 + q * 4];
#pragma unroll
    for (int i = 0; i < 4; i++) {
        int m = m0 + wm + i * 16 + l15;
        int posx = xp[m] * 16, posy = yp[m] * 16;
#pragma unroll
        for (int j = 0; j < 4; j++) {
            float v0 = acc[i][j][0] + bj[j].x;
            float v1 = acc[i][j][1] + bj[j].y;
            float v2 = acc[i][j][2] + bj[j].z;
            float v3 = acc[i][j][3] + bj[j].w;
            // head-dim dd = j*16 + q*4 + r  (dd<32 -> x_pos, else y_pos)
            int pos = (j < 2) ? posx : posy;
            int t2 = (j & 1) * 8 + q * 2;
            float2 cs0 = csT[pos + t2];
            float2 cs1 = csT[pos + t2 + 1];
            float r0 = v0 * cs0.x - v1 * cs0.y;
            float r1 = v1 * cs0.x + v0 * cs0.y;
            float r2 = v2 * cs1.x - v3 * cs1.y;
            float r3 = v3 * cs1.x + v2 * cs1.y;
            ushort4 o;
            o.x = f2bf(r0); o.y = f2bf(r1); o.z = f2bf(r2); o.w = f2bf(r3);
            *(ushort4*)&seq[(size_t)m * NCOL + n0 + wn + j * 16 + q * 4] = o;
        }
    }
}

// ---------------- attention: out[b][h][m][n] = (Q.Kt)/8 - tril - mask ------
// swapped operands: acc rows = n (q*4+r), cols = m (l15)  -> float4 stores
__global__ __launch_bounds__(256) void k_attn(const unsigned short* __restrict__ seq,
                                              const int* __restrict__ mask,
                                              float* __restrict__ out) {
    __shared__ __align__(16) unsigned short Qs[128 * 64];
    __shared__ __align__(16) unsigned short Ks[128 * 64];
    int tid = threadIdx.x;
    int bh = blockIdx.z;
    int b = bh / NH, h = bh - b * NH;
    int m0 = blockIdx.x * 128, n0 = blockIdx.y * 128;
    const unsigned short* qbase = seq + (size_t)b * SEQ * NCOL + h * 128;

#pragma unroll
    for (int it = 0; it < 4; ++it) {
        int c = it * 256 + tid;
        int r = c >> 3, cl = c & 7;
        int cg = cl ^ (r & 7);
        gload_lds16(qbase + (size_t)(m0 + r) * NCOL + cg * 8, Qs + c * 8);
        gload_lds16(qbase + (size_t)(n0 + r) * NCOL + 64 + cg * 8, Ks + c * 8);
    }
    __syncthreads();

    int wave = tid >> 6, lane = tid & 63;
    int l15 = lane & 15, q = lane >> 4;
    int wm = (wave >> 1) * 64, wn = (wave & 1) * 64;

    f32x4_t acc[4][4];
#pragma unroll
    for (int i = 0; i < 4; i++)
#pragma unroll
        for (int j = 0; j < 4; j++) acc[i][j] = (f32x4_t){0.f, 0.f, 0.f, 0.f};

#pragma unroll
    for (int ks = 0; ks < 2; ++ks) {
        bf16x8_t af[4], bfr[4];
#pragma unroll
        for (int i = 0; i < 4; i++) {
            int r = wm + i * 16 + l15;
            int cl = (ks * 4 + q) ^ (r & 7);
            af[i] = *(const bf16x8_t*)&Qs[r * 64 + cl * 8];
        }
#pragma unroll
        for (int j = 0; j < 4; j++) {
            int r = wn + j * 16 + l15;
            int cl = (ks * 4 + q) ^ (r & 7);
            bfr[j] = *(const bf16x8_t*)&Ks[r * 64 + cl * 8];
        }
#pragma unroll
        for (int i = 0; i < 4; i++)
#pragma unroll
            for (int j = 0; j < 4; j++)
                acc[i][j] = __builtin_amdgcn_mfma_f32_16x16x32_bf16(bfr[j], af[i], acc[i][j], 0, 0, 0);
    }

    const int* mrow = mask + b * SEQ;
    bool ent = (h < 2);
    size_t obase = (size_t)bh * SEQ * SEQ;
    int4 mn[4];
#pragma unroll
    for (int j = 0; j < 4; j++)
        mn[j] = *(const int4*)&mrow[n0 + wn + j * 16 + q * 4];
#pragma unroll
    for (int i = 0; i < 4; i++) {
        int m = m0 + wm + i * 16 + l15;
        bool mz = (mrow[m] == 0);
#pragma unroll
        for (int j = 0; j < 4; j++) {
            int nb = n0 + wn + j * 16 + q * 4;
            float4 v;
            v.x = acc[i][j][0] * 0.125f;
            v.y = acc[i][j][1] * 0.125f;
            v.z = acc[i][j][2] * 0.125f;
            v.w = acc[i][j][3] * 0.125f;
            if (ent) {
                if (m > nb)     v.x -= 1.25e11f;
                if (m > nb + 1) v.y -= 1.25e11f;
                if (m > nb + 2) v.z -= 1.25e11f;
                if (m > nb + 3) v.w -= 1.25e11f;
            }
            if (mz || mn[j].x == 0) v.x = -INFINITY;
            if (mz || mn[j].y == 0) v.y = -INFINITY;
            if (mz || mn[j].z == 0) v.z = -INFINITY;
            if (mz || mn[j].w == 0) v.w = -INFINITY;
            *(float4*)&out[obase + (size_t)m * SEQ + nb] = v;
        }
    }
}

extern "C" void kernel_launch(void* const* d_in, const int* in_sizes, int n_in,
                              void* d_out, int out_size, void* d_ws, size_t ws_size,
                              hipStream_t stream) {
    const float* x      = (const float*)d_in[0];
    const int*   mask   = (const int*)d_in[1];
    const int*   xp     = (const int*)d_in[2];
    const int*   yp     = (const int*)d_in[3];
    const float* W_ent  = (const float*)d_in[4];
    const float* b_ent  = (const float*)d_in[5];
    const float* W_head = (const float*)d_in[6];
    const float* b_head = (const float*)d_in[7];
    const float* W_tail = (const float*)d_in[8];
    const float* b_tail = (const float*)d_in[9];
    float* out = (float*)d_out;

    char* ws = (char*)d_ws;
    size_t off = 0;
    auto alloc = [&](size_t bytes) {
        void* p = ws + off;
        off += (bytes + 255) & ~(size_t)255;
        return p;
    };
    float2* csT = (float2*)alloc(16384 * 8);
    unsigned short* xb  = (unsigned short*)alloc((size_t)M_TOK * HID * 2);
    unsigned short* Wt  = (unsigned short*)alloc((size_t)NCOL * HID * 2);
    float* ball = (float*)alloc(NCOL * 4);
    unsigned short* seq = (unsigned short*)alloc((size_t)M_TOK * NCOL * 2);

    k_prep<<<2137, 256, 0, stream>>>(x, xb, csT, b_ent, b_head, b_tail, ball);
    k_cvt_w<<<dim3(200, 32), dim3(32, 32), 0, stream>>>(W_ent, W_head, W_tail, Wt);
    k_gemm1<<<dim3(16, 50), 256, 0, stream>>>(xb, Wt, ball, xp, yp, csT, seq);
    k_attn<<<dim3(4, 4, 200), 256, 0, stream>>>(seq, mask, out);
}